// Round 12
// baseline (77.720 us; speedup 1.0000x reference)
//
#include <hip/hip_runtime.h>

// BoundaryLoss: exact separable squared EDT, pos+neg masks MERGED per plane
// (complement masks share one scan; distances packed u16x2 in one u32 g).
// Three launches. x (8,4,256,256) f32; y (8,1,256,256) i32; out scalar f32.
//
// dist_map: +d(pos) at neg px, (1-d(neg)) at pos px, 0 if class absent.
// All squared distances are exact integers (<=130050): sqrtf + f32 mul + f64
// accumulation reproduces the np reference to ~1e-10 (absmax 0.0 measured).
//
// Measured ledger: R11 = 73.7 (best): vpass-1024 lb(256,4) ~3.5 + hpass-2048
//   x8rows ~8.5 + finalize ~4 + harness floor ~53 (268MB re-poison @82% HBM).
//   R6/R10: fused designs lose (waves/CU controls latency-bound scans).
//   R7: threadfence per block / (256,8) VGPR cap = disaster. R9: atomic tail
//   +5us vs separate finalize. This round: merge complement masks (halve
//   grids + y-traffic; search work unchanged; math bit-identical).

#define HH 256
#define WW 256
#define NPIX (HH*WW)
#define NPL 32              // 8 b * 4 k merged planes
#define BIG (1 << 27)

// ---------------- Kernel 1: vertical pass, dual-mask segmented scan --------
// grid: 32 planes * 16 col-chunks = 512 blocks, 256 thr, lb(256,4).
// thread = (seg 0..15) x (col 0..15); 16 rows each. Tracks nearest y==k
// (mask0) AND y!=k (mask1) in one scan; packs d0^2|d1^2 as u16x2 into g.
#define SEGS 16
#define RSEG 16
#define CPB 16

__global__ __launch_bounds__(256, 4) void edt_vpass(
        const int* __restrict__ y, unsigned int* __restrict__ g) {
    __shared__ unsigned int d[HH][CPB + 1];     // packed du0|du1<<16, +1 pad
    __shared__ short segLast0[SEGS][CPB], segFirst0[SEGS][CPB];
    __shared__ short segLast1[SEGS][CPB], segFirst1[SEGS][CPB];

    int bid = blockIdx.x;
    int pm  = bid >> 4;                 // plane 0..31
    int cc  = bid & 15;                 // col chunk
    int b   = pm >> 2;
    int k   = pm & 3;

    int t   = threadIdx.x;
    int col = t & (CPB - 1);
    int seg = t >> 4;
    int w   = cc * CPB + col;
    int h0  = seg * RSEG;

    const int* yp = y + b * NPIX;
    unsigned int* gp = g + (size_t)pm * NPIX;

    // forward (downward) local scan — every row updates exactly one mask
    int last0 = -1000, first0 = 1000, last1 = -1000, first1 = 1000;
    for (int i = 0; i < RSEG; ++i) {
        int h   = h0 + i;
        int lab = yp[h * WW + w];
        if (lab == k) { last0 = h; if (first0 > 900) first0 = h; }
        else          { last1 = h; if (first1 > 900) first1 = h; }
        unsigned int du0 = (unsigned int)min(h - last0, 1000);
        unsigned int du1 = (unsigned int)min(h - last1, 1000);
        d[h][col] = du0 | (du1 << 16);
    }
    segLast0[seg][col] = (short)last0;  segFirst0[seg][col] = (short)first0;
    segLast1[seg][col] = (short)last1;  segFirst1[seg][col] = (short)first1;
    __syncthreads();

    // cross-segment prefix for both masks
    int prevLast0 = -1000, prevLast1 = -1000;
    for (int s = seg - 1; s >= 0; --s) {
        int v = segLast0[s][col];
        if (v >= 0) { prevLast0 = v; break; }
    }
    for (int s = seg - 1; s >= 0; --s) {
        int v = segLast1[s][col];
        if (v >= 0) { prevLast1 = v; break; }
    }
    int nextFirst0 = 1000, nextFirst1 = 1000;
    for (int s = seg + 1; s < SEGS; ++s) {
        int v = segFirst0[s][col];
        if (v < 900) { nextFirst0 = v; break; }
    }
    for (int s = seg + 1; s < SEGS; ++s) {
        int v = segFirst1[s][col];
        if (v < 900) { nextFirst1 = v; break; }
    }

    // backward scan: combine, square, pack, store
    int nd0 = nextFirst0, nd1 = nextFirst1;
    for (int i = RSEG - 1; i >= 0; --i) {
        int h = h0 + i;
        unsigned int pk = d[h][col];
        int du0 = (int)(pk & 0xFFFFu), du1 = (int)(pk >> 16);
        if (du0 == 0) nd0 = h;
        if (du1 == 0) nd1 = h;
        int m0 = min(min(min(du0, h - prevLast0), nd0 - h), 256);
        int m1 = min(min(min(du1, h - prevLast1), nd1 - h), 256);
        unsigned int v0 = (m0 > 255) ? 0xFFFFu : (unsigned int)(m0 * m0);
        unsigned int v1 = (m1 > 255) ? 0xFFFFu : (unsigned int)(m1 * m1);
        gp[h * WW + w] = v0 | (v1 << 16);       // <= 65025 each; 0xFFFF sentinel
    }
}

// ---------------- Kernel 2: horizontal pass (both masks) + contraction -----
// grid: 32 planes * 32 row-chunks = 1024 blocks, 256 thr, 8 rows ->
// 16.6KB LDS, 8 blk/CU, 32 waves/CU. NO launch_bounds/fence/atomics.
// Batched pruned exact search per mask: min_j tile[j]+(w-j)^2, radii 4 at a
// time (8 LDS loads overlapped), prune per batch (lossless). Edge clamp
// exact. Pixel contributes to exactly one mask (complements) -> one x load.
#define ROWS_PER_BLK 8
#define NBLK2 1024

__global__ void edt_hpass(const unsigned int* __restrict__ g,
                          const float* __restrict__ x,
                          double* __restrict__ bsums) {
    __shared__ int t0[ROWS_PER_BLK][WW];     // mask0 (y==k), sentinel -> BIG
    __shared__ int t1[ROWS_PER_BLK][WW];     // mask1 (y!=k)
    __shared__ double wsum[4];

    int bid = blockIdx.x;
    int pm  = bid >> 5;                  // plane 0..31
    int rc  = bid & 31;
    int r0  = rc * ROWS_PER_BLK;
    int t   = threadIdx.x;               // = column w

    const unsigned int* gp = g + (size_t)pm * NPIX + r0 * WW;
    const float* xp = x + (size_t)pm * NPIX;

    // tile fill: one u32 per px carries both masks; 8*256 = 8 iters
    #pragma unroll
    for (int i2 = 0; i2 < 8; ++i2) {
        int idx = i2 * 256 + t;
        int row = idx >> 8;
        int c   = idx & 255;
        unsigned int v = gp[row * WW + c];
        int v0 = (int)(v & 0xFFFFu);
        int v1 = (int)(v >> 16);
        t0[row][c] = (v0 == 0xFFFF) ? BIG : v0;
        t1[row][c] = (v1 == 0xFFFF) ? BIG : v1;
    }
    __syncthreads();

    double lsum = 0.0;
    for (int i = 0; i < ROWS_PER_BLK; ++i) {
        int best0 = t0[i][t];
        #pragma unroll 1
        for (int bs = 1; bs < WW; bs += 4) {
            if (bs * bs >= best0) break;         // lossless prune
            int m = best0;
            #pragma unroll
            for (int u = 0; u < 4; ++u) {
                int r  = bs + u;
                int rr = r * r;
                int jl = max(t - r, 0);
                int jr = min(t + r, WW - 1);
                m = min(m, t0[i][jl] + rr);
                m = min(m, t0[i][jr] + rr);
            }
            best0 = m;
        }
        int best1 = t1[i][t];
        #pragma unroll 1
        for (int bs = 1; bs < WW; bs += 4) {
            if (bs * bs >= best1) break;
            int m = best1;
            #pragma unroll
            for (int u = 0; u < 4; ++u) {
                int r  = bs + u;
                int rr = r * r;
                int jl = max(t - r, 0);
                int jr = min(t + r, WW - 1);
                m = min(m, t1[i][jl] + rr);
                m = min(m, t1[i][jr] + rr);
            }
            best1 = m;
        }
        // c0: neg px, +d(pos).  c1: pos px, (1-d(neg)).  Mutually exclusive.
        // Class absent: best0=BIG & best1=0 -> both skip (has_pos semantics).
        bool c0 = (best0 > 0) && (best0 < BIG);
        bool c1 = (best1 > 0) && (best1 < BIG);
        if (c0 | c1) {
            float xv   = xp[(r0 + i) * WW + t];
            float term = c0 ? sqrtf((float)best0)
                            : (1.0f - sqrtf((float)best1));  // == -(d-1)
            lsum += (double)(xv * term);                     // f64 accumulate
        }
    }

    // block reduction: wave butterfly then 4 wave leaders
    for (int off = 32; off > 0; off >>= 1)
        lsum += __shfl_down(lsum, off, 64);
    int lane = t & 63, wv = t >> 6;
    if (lane == 0) wsum[wv] = lsum;
    __syncthreads();
    if (t == 0) bsums[bid] = wsum[0] + wsum[1] + wsum[2] + wsum[3];
}

// ---------------- Kernel 3: final reduce + mean ----------------------------
__global__ void edt_finalize(const double* __restrict__ bsums, float* __restrict__ out) {
    __shared__ double wsum[4];
    int t = threadIdx.x;
    double s = 0.0;
    for (int i = t; i < NBLK2; i += 256) s += bsums[i];
    for (int off = 32; off > 0; off >>= 1)
        s += __shfl_down(s, off, 64);
    int lane = t & 63, wv = t >> 6;
    if (lane == 0) wsum[wv] = s;
    __syncthreads();
    if (t == 0)
        out[0] = (float)((wsum[0] + wsum[1] + wsum[2] + wsum[3]) * (1.0 / 2097152.0));
}

extern "C" void kernel_launch(void* const* d_in, const int* in_sizes, int n_in,
                              void* d_out, int out_size, void* d_ws, size_t ws_size,
                              hipStream_t stream) {
    const float* x = (const float*)d_in[0];
    const int*   y = (const int*)d_in[1];
    float* out = (float*)d_out;

    // ws layout: [0, 8MB) u32 packed g planes; [8MB, 8MB+8KB) f64 block sums
    unsigned int* g = (unsigned int*)d_ws;
    double* bsums = (double*)((char*)d_ws + (size_t)NPL * NPIX * sizeof(unsigned int));

    edt_vpass   <<<512,   256, 0, stream>>>(y, g);
    edt_hpass   <<<NBLK2, 256, 0, stream>>>(g, x, bsums);
    edt_finalize<<<1,     256, 0, stream>>>(bsums, out);
}

// Round 13
// 75.280 us; speedup vs baseline: 1.0324x; 1.0324x over previous
//
#include <hip/hip_runtime.h>

// BoundaryLoss: exact separable squared EDT per (b,k,which) plane-mask,
// fused with x*dist contraction. Three launches, measured-best pieces only.
// === R11 MEASURED OPTIMUM (73.7us), reverted after R12 mask-merge regressed ===
//
// x (8,4,256,256) f32; y (8,1,256,256) i32 in [0,4). out: scalar f32 mean.
// dist_map: +d(pos) at neg px, (1-d(neg)) at pos px, 0 if class absent.
// All squared distances are exact integers (<=130050): sqrtf + f32 mul + f64
// accumulation reproduces the np reference to ~1e-10 (absmax 0.0 measured).
//
// Measured ledger:  R11 = 73.7 total (floor ~53 + ours ~15-20).
//   R6 whole-plane fuse = 65us kernel; R10 chunk fuse (4 w/CU) = 115us
//     -> waves/CU controls latency-bound scans; fusion loses.
//   R7 vpass-1024 lb(256,4) ~3.5us <- kept here.
//   R7 hpass +threadfence +(256,8) VGPR=8 = 52us <- never do either.
//   R9 atomic tail in hpass = +5us vs separate finalize <- keep split.
//   R12 merged complement masks = +4us (serializes easy+hard searches
//     in one thread; split blocks load-balance across CUs) <- keep split.

#define HH 256
#define WW 256
#define NPIX (HH*WW)
#define NPM 64              // 8 b * 4 k * 2 which
#define BIG (1 << 27)

// ---------------- Kernel 1: vertical pass (segmented column scan) ----------
// 64 pm * 16 col-chunks = 1024 blocks, 256 thr, lb(256,4)
// -> 4 blk/CU, 16 waves/CU. thread = (seg 0..15) x (col 0..15), 16 rows each.
#define SEGS 16
#define RSEG 16
#define CPB 16

__global__ __launch_bounds__(256, 4) void edt_vpass(
        const int* __restrict__ y, unsigned short* __restrict__ g) {
    __shared__ unsigned short d[HH][CPB + 1];   // pad
    __shared__ short segLast[SEGS][CPB];        // last feature row (-1000 none)
    __shared__ short segFirst[SEGS][CPB];       // first feature row (1000 none)

    int bid   = blockIdx.x;
    int pm    = bid >> 4;               // 0..63
    int cc    = bid & 15;               // col chunk
    int which = pm & 1;                 // 0: feature=(y==k), 1: feature=(y!=k)
    int plane = pm >> 1;
    int b     = plane >> 2;
    int k     = plane & 3;

    int t   = threadIdx.x;
    int col = t & (CPB - 1);
    int seg = t >> 4;
    int w   = cc * CPB + col;
    int h0  = seg * RSEG;

    const int* yp = y + b * NPIX;
    unsigned short* gp = g + (size_t)pm * NPIX;

    // forward (downward) local scan
    int lastL = -1000, firstL = 1000;
    for (int i = 0; i < RSEG; ++i) {
        int h   = h0 + i;
        int lab = yp[h * WW + w];
        int feat = ((lab == k) ? 1 : 0) ^ which;
        if (feat) { lastL = h; if (firstL > 900) firstL = h; }
        d[h][col] = (unsigned short)min(h - lastL, 1000);
    }
    segLast[seg][col]  = (short)lastL;
    segFirst[seg][col] = (short)firstL;
    __syncthreads();

    // cross-segment prefix: nearest feature above / below my segment
    int prevLast = -1000;
    for (int s = seg - 1; s >= 0; --s) {
        int v = segLast[s][col];
        if (v >= 0) { prevLast = v; break; }
    }
    int nextFirst = 1000;
    for (int s = seg + 1; s < SEGS; ++s) {
        int v = segFirst[s][col];
        if (v < 900) { nextFirst = v; break; }
    }

    // backward scan + combine + square + store
    int nd = nextFirst;
    for (int i = RSEG - 1; i >= 0; --i) {
        int h  = h0 + i;
        int du = d[h][col];
        if (du == 0) nd = h;
        int dup = min(du, h - prevLast);
        int ddn = nd - h;
        int m   = min(min(dup, ddn), 256);
        gp[h * WW + w] = (m > 255) ? (unsigned short)0xFFFF
                                   : (unsigned short)(m * m);   // <= 65025
    }
}

// ---------------- Kernel 2: horizontal pass + fused contraction ------------
// 64 pm * 32 row-chunks = 2048 blocks, 256 thr, 8 rows -> 8KB tile,
// 8 blk/CU, 32 waves/CU. NO launch_bounds, NO fence, NO atomics.
// Batched pruned exact search: min_j g[j]+(w-j)^2, radii 4 at a time
// (8 LDS loads overlapped), prune per batch (lossless). Edge clamp exact.
#define ROWS_PER_BLK 8
#define NBLK2 2048

__global__ void edt_hpass(const unsigned short* __restrict__ g,
                          const float* __restrict__ x,
                          double* __restrict__ bsums) {
    __shared__ int tile[ROWS_PER_BLK][WW];   // sentinel pre-mapped to BIG
    __shared__ double wsum[4];

    int bid   = blockIdx.x;
    int pm    = bid >> 5;
    int rc    = bid & 31;
    int r0    = rc * ROWS_PER_BLK;
    int which = pm & 1;
    int plane = pm >> 1;
    int t     = threadIdx.x;   // = w

    const unsigned short* gp = g + (size_t)pm * NPIX;
    const float* xp = x + (size_t)plane * NPIX;

    // tile fill: uint loads (2 px); 8 rows * 128 uints = 1024 = 4*256
    const unsigned int* gp32 = (const unsigned int*)(gp + r0 * WW);
    #pragma unroll
    for (int i2 = 0; i2 < 4; ++i2) {
        int idx = i2 * 256 + t;
        int row = idx >> 7;
        int c2  = idx & 127;
        unsigned int v = gp32[row * 128 + c2];
        int v0 = (int)(v & 0xFFFFu);
        int v1 = (int)(v >> 16);
        tile[row][2 * c2]     = (v0 == 0xFFFF) ? BIG : v0;
        tile[row][2 * c2 + 1] = (v1 == 0xFFFF) ? BIG : v1;
    }
    __syncthreads();

    double lsum = 0.0;
    for (int i = 0; i < ROWS_PER_BLK; ++i) {
        int best = tile[i][t];
        #pragma unroll 1
        for (int bs = 1; bs < WW; bs += 4) {
            if (bs * bs >= best) break;          // lossless prune
            int m = best;
            #pragma unroll
            for (int u = 0; u < 4; ++u) {
                int r  = bs + u;
                int rr = r * r;
                int jl = max(t - r, 0);
                int jr = min(t + r, WW - 1);
                m = min(m, tile[i][jl] + rr);
                m = min(m, tile[i][jr] + rr);
            }
            best = m;
        }
        // best==0: feature px (term 0). best>=BIG: class absent (has_pos).
        if (best > 0 && best < BIG) {
            float xv   = xp[(r0 + i) * WW + t];        // conditional (R4 form)
            float dd   = sqrtf((float)best);           // exact-int sqrt
            float term = which ? (1.0f - dd) : dd;     // == -(d-1) exactly
            lsum += (double)(xv * term);               // f32 product, f64 acc
        }
    }

    // block reduction: wave butterfly then 4 wave leaders
    for (int off = 32; off > 0; off >>= 1)
        lsum += __shfl_down(lsum, off, 64);
    int lane = t & 63, wv = t >> 6;
    if (lane == 0) wsum[wv] = lsum;
    __syncthreads();
    if (t == 0) bsums[bid] = wsum[0] + wsum[1] + wsum[2] + wsum[3];
}

// ---------------- Kernel 3: final reduce + mean ----------------------------
__global__ void edt_finalize(const double* __restrict__ bsums, float* __restrict__ out) {
    __shared__ double wsum[4];
    int t = threadIdx.x;
    double s = 0.0;
    for (int i = t; i < NBLK2; i += 256) s += bsums[i];
    for (int off = 32; off > 0; off >>= 1)
        s += __shfl_down(s, off, 64);
    int lane = t & 63, wv = t >> 6;
    if (lane == 0) wsum[wv] = s;
    __syncthreads();
    if (t == 0)
        out[0] = (float)((wsum[0] + wsum[1] + wsum[2] + wsum[3]) * (1.0 / 2097152.0));
}

extern "C" void kernel_launch(void* const* d_in, const int* in_sizes, int n_in,
                              void* d_out, int out_size, void* d_ws, size_t ws_size,
                              hipStream_t stream) {
    const float* x = (const float*)d_in[0];
    const int*   y = (const int*)d_in[1];
    float* out = (float*)d_out;

    // ws layout: [0, 8MB) u16 g planes; [8MB, 8MB+16KB) f64 block sums
    unsigned short* g = (unsigned short*)d_ws;
    double* bsums = (double*)((char*)d_ws + (size_t)NPM * NPIX * sizeof(unsigned short));

    edt_vpass   <<<1024,  256, 0, stream>>>(y, g);
    edt_hpass   <<<NBLK2, 256, 0, stream>>>(g, x, bsums);
    edt_finalize<<<1,     256, 0, stream>>>(bsums, out);
}